// Round 1
// baseline (8287.437 us; speedup 1.0000x reference)
//
#include <hip/hip_runtime.h>
#include <math.h>

#define CC 64          // channels
#define VV 25          // graph nodes
#define VP 26          // padded LDS row length
#define T_TOTAL 64
#define OBS 32
#define BATCH 512
#define NTHREADS 256
#define TV (T_TOTAL * VV)   // stride between channels in global layout [B][C][T][V]

__device__ __forceinline__ float tanh_fast(float x) {
    // tanh(x) = (e^{2x}-1)/(e^{2x}+1), clamp 2x to +-30 (tanh saturates to fp32 1.0)
    float t = fminf(fmaxf(2.0f * x, -30.0f), 30.0f);
    float e = __expf(t);
    return (e - 1.0f) / (e + 1.0f);
}

// dst[c][v] = sum_u (src[c][u] + pe[c]) * A[v][u]   (pe optional, fused via rowsum(A))
__device__ __forceinline__ void amul(float* __restrict__ dst, const float* __restrict__ srcb,
                                     const float* __restrict__ As, const float* __restrict__ rsA,
                                     const float* __restrict__ pe, int tid)
{
    int c = tid >> 2, vs = tid & 3;
    float acc[7];
    float pec = (pe != nullptr) ? pe[c] : 0.0f;
    #pragma unroll
    for (int j = 0; j < 7; ++j) {
        int v = vs + 4 * j;
        acc[j] = (pe != nullptr && v < VV) ? pec * rsA[v] : 0.0f;
    }
    #pragma unroll
    for (int u = 0; u < VV; ++u) {
        float x = srcb[c * VP + u];
        #pragma unroll
        for (int j = 0; j < 7; ++j) {
            int v = vs + 4 * j;
            if (v < VV) acc[j] = fmaf(x, As[v * VP + u], acc[j]);
        }
    }
    #pragma unroll
    for (int j = 0; j < 7; ++j) {
        int v = vs + 4 * j;
        if (v < VV) dst[c * VP + v] = acc[j];
    }
    __syncthreads();
}

// dst[o][v] = act( sum_c W[o][c]*src[c][v] + B[o] )
__device__ __forceinline__ void wmul(float* __restrict__ dst, const float* __restrict__ srcb,
                                     const float* __restrict__ Wg, const float* __restrict__ Bg,
                                     bool dotanh, int tid)
{
    int o = tid >> 2, vs = tid & 3;
    float acc[7];
    float b = Bg[o];
    #pragma unroll
    for (int j = 0; j < 7; ++j) acc[j] = b;
    #pragma unroll 8
    for (int cc = 0; cc < CC; ++cc) {
        float w = Wg[o * CC + cc];
        #pragma unroll
        for (int j = 0; j < 7; ++j) {
            int v = vs + 4 * j;
            if (v < VV) acc[j] = fmaf(w, srcb[cc * VP + v], acc[j]);
        }
    }
    #pragma unroll
    for (int j = 0; j < 7; ++j) {
        int v = vs + 4 * j;
        if (v < VV) {
            float r = acc[j];
            dst[o * VP + v] = dotanh ? tanh_fast(r) : r;
        }
    }
    __syncthreads();
}

// f(x): input in s0 (destroyed), scratch s1, result -> out. out may not alias s1.
__device__ __forceinline__ void ode_f(float* out, float* s0, float* s1,
                                      const float* As, const float* rsA, const float* pe0,
                                      const float* W1, const float* B1,
                                      const float* W2, const float* B2,
                                      const float* W3, const float* B3,
                                      const float* W4, const float* B4, int tid)
{
    amul(s1, s0, As, rsA, pe0, tid);
    wmul(s0, s1, W1, B1, true, tid);
    amul(s1, s0, As, rsA, nullptr, tid);
    wmul(s0, s1, W2, B2, true, tid);
    amul(s1, s0, As, rsA, nullptr, tid);
    wmul(s0, s1, W3, B3, true, tid);
    wmul(out, s0, W4, B4, false, tid);
}

__global__ void __launch_bounds__(NTHREADS)
rk4_kernel(const float* __restrict__ src, float* __restrict__ dst,
           const float* __restrict__ Ag, const float* __restrict__ pe,
           const float* __restrict__ W1, const float* __restrict__ B1,
           const float* __restrict__ W2, const float* __restrict__ B2,
           const float* __restrict__ W3, const float* __restrict__ B3,
           const float* __restrict__ W4, const float* __restrict__ B4,
           int nt, int src_t0, int dst_t0, int pe_row)
{
    __shared__ float y[CC * VP], k1[CC * VP], k2[CC * VP], k3[CC * VP];
    __shared__ float s0[CC * VP], s1[CC * VP];
    __shared__ float As[VV * VP], rsA[VV];

    int tid = threadIdx.x;
    int blk = blockIdx.x;
    int b  = blk / nt;
    int tt = blk - b * nt;
    int t_src = src_t0 + tt;
    int t_dst = dst_t0 + tt;

    const float* pe0 = pe + pe_row * CC;
    const float* pe1 = pe0 + CC;

    // stage A into LDS
    for (int i = tid; i < VV * VV; i += NTHREADS) {
        int v = i / VV, u = i - v * VV;
        As[v * VP + u] = Ag[i];
    }
    __syncthreads();
    if (tid < VV) {
        float s = 0.0f;
        #pragma unroll
        for (int u = 0; u < VV; ++u) s += As[tid * VP + u];
        rsA[tid] = s;
    }

    // load y, and s0 = y
    const float* srcp = src + (size_t)b * CC * TV + (size_t)t_src * VV;
    for (int i = tid; i < CC * VV; i += NTHREADS) {
        int c = i / VV, v = i - c * VV;
        float val = srcp[(size_t)c * TV + v];
        y[c * VP + v]  = val;
        s0[c * VP + v] = val;
    }
    __syncthreads();

    // k1 = f(y, pe0)
    ode_f(k1, s0, s1, As, rsA, pe0, W1, B1, W2, B2, W3, B3, W4, B4, tid);

    // s0 = y + k1/3
    for (int i = tid; i < CC * VV; i += NTHREADS) {
        int c = i / VV, v = i - c * VV; int id = c * VP + v;
        s0[id] = y[id] + k1[id] * (1.0f / 3.0f);
    }
    __syncthreads();
    ode_f(k2, s0, s1, As, rsA, pe0, W1, B1, W2, B2, W3, B3, W4, B4, tid);

    // s0 = y - k1/3 + k2
    for (int i = tid; i < CC * VV; i += NTHREADS) {
        int c = i / VV, v = i - c * VV; int id = c * VP + v;
        s0[id] = y[id] - k1[id] * (1.0f / 3.0f) + k2[id];
    }
    __syncthreads();
    ode_f(k3, s0, s1, As, rsA, pe0, W1, B1, W2, B2, W3, B3, W4, B4, tid);

    // s0 = y + k1 - k2 + k3 ; fold S = k1 + 3(k2+k3) into k1
    for (int i = tid; i < CC * VV; i += NTHREADS) {
        int c = i / VV, v = i - c * VV; int id = c * VP + v;
        float a = k1[id], bb = k2[id], cc2 = k3[id];
        s0[id] = y[id] + a - bb + cc2;
        k1[id] = a + 3.0f * (bb + cc2);
    }
    __syncthreads();
    // k4 -> k2 (uses pe1)
    ode_f(k2, s0, s1, As, rsA, pe1, W1, B1, W2, B2, W3, B3, W4, B4, tid);

    // dst = y + (S + k4)/8
    float* dstp = dst + (size_t)b * CC * TV + (size_t)t_dst * VV;
    for (int i = tid; i < CC * VV; i += NTHREADS) {
        int c = i / VV, v = i - c * VV; int id = c * VP + v;
        dstp[(size_t)c * TV + v] = y[id] + (k1[id] + k2[id]) * 0.125f;
    }
}

__global__ void pe_kernel(float* __restrict__ pe) {
    int idx = blockIdx.x * blockDim.x + threadIdx.x;
    if (idx >= T_TOTAL * CC) return;
    int t = idx >> 6, c = idx & 63;
    int i2 = c & ~1;  // even index of the pair
    float div = expf((float)i2 * (-logf(10000.0f) / (float)CC));
    float arg = (float)t * div;
    pe[idx] = (c & 1) ? cosf(arg) : sinf(arg);
}

extern "C" void kernel_launch(void* const* d_in, const int* in_sizes, int n_in,
                              void* d_out, int out_size, void* d_ws, size_t ws_size,
                              hipStream_t stream) {
    const float* z  = (const float*)d_in[0];
    const float* A  = (const float*)d_in[1];
    const float* w1 = (const float*)d_in[2];
    const float* b1 = (const float*)d_in[3];
    const float* w2 = (const float*)d_in[4];
    const float* b2 = (const float*)d_in[5];
    const float* w3 = (const float*)d_in[6];
    const float* b3 = (const float*)d_in[7];
    const float* w4 = (const float*)d_in[8];
    const float* b4 = (const float*)d_in[9];
    float* out = (float*)d_out;
    float* pe  = (float*)d_ws;   // 64*64 floats

    pe_kernel<<<(T_TOTAL * CC + 255) / 256, 256, 0, stream>>>(pe);

    // z_hat: t = 0..31, all with pe rows 0,1
    rk4_kernel<<<BATCH * OBS, NTHREADS, 0, stream>>>(
        z, out, A, pe, w1, b1, w2, b2, w3, b3, w4, b4,
        OBS, /*src_t0=*/0, /*dst_t0=*/0, /*pe_row=*/0);

    // autoregressive scan: 32 sequential steps
    for (int i = 0; i < 32; ++i) {
        const float* srcp = (i == 0) ? z : out;
        rk4_kernel<<<BATCH, NTHREADS, 0, stream>>>(
            srcp, out, A, pe, w1, b1, w2, b2, w3, b3, w4, b4,
            1, /*src_t0=*/31 + i, /*dst_t0=*/32 + i, /*pe_row=*/i);
    }
}